// Round 1
// baseline (1367.961 us; speedup 1.0000x reference)
//
#include <hip/hip_runtime.h>
#include <cfloat>
#include <cmath>

#define NB 2
#define NC 34
#define NH 512
#define NW 1024
#define HWSZ (NH*NW)          // 524288 = 2^19
#define TK 200
#define CAPC 49152            // >= max possible 7x7 strict local maxima (128*256=32768)
#define STAGE 6144            // LDS staging capacity for top-k (48KB)

// ---------------- K1: softmax argmax + max + denom ----------------
__global__ __launch_bounds__(256) void k_seg(const float* __restrict__ logits,
                                             float* __restrict__ segmap_out,
                                             int* __restrict__ segid,
                                             float* __restrict__ mArr,
                                             float* __restrict__ dArr) {
    int p = blockIdx.x * 256 + threadIdx.x;
    if (p >= NB * HWSZ) return;
    int b = p >> 19;
    int pix = p & (HWSZ - 1);
    const float* base = logits + (size_t)b * NC * HWSZ + pix;
    float v[NC];
#pragma unroll
    for (int c = 0; c < NC; c++) v[c] = base[(size_t)c * HWSZ];
    float m = -FLT_MAX; int bc = 0;
#pragma unroll
    for (int c = 0; c < NC; c++) { if (v[c] > m) { m = v[c]; bc = c; } }
    float den = 0.f;
#pragma unroll
    for (int c = 0; c < NC; c++) den += expf(v[c] - m);
    segmap_out[p] = (float)bc;
    segid[p] = bc;
    mArr[p] = m;
    dArr[p] = den;
}

// ---------------- K2: vote map (exact f32 order as reference) ----------------
__global__ __launch_bounds__(256) void k_vote(const float* __restrict__ reg,
                                              float* __restrict__ vote) {
    int p = blockIdx.x * 256 + threadIdx.x;
    if (p >= NB * HWSZ) return;
    int b = p >> 19;
    int pix = p & (HWSZ - 1);
    int y = pix >> 10;
    int x = pix & (NW - 1);
    const float* r0 = reg + (size_t)b * 2 * HWSZ;
    const float* r1 = r0 + HWSZ;
    float acc = 0.f;
#pragma unroll
    for (int i = 0; i < 11; i++) {
        int di = i - 5;
        int yy = y + di;
#pragma unroll
        for (int j = 0; j < 11; j++) {
            int dj = j - 5;
            if (di * di + dj * dj > 25) continue;   // cmask, exact integer test
            int xx = x + dj;
            bool in = (yy >= 0) && (yy < NH) && (xx >= 0) && (xx < NW);
            float rx = 0.f, ry = 0.f;
            if (in) {
                int q = yy * NW + xx;
                rx = r0[q];
                ry = r1[q];
            }
            float dx = __fsub_rn((float)dj, rx);
            float dy = __fsub_rn((float)di, ry);
            float s  = __fadd_rn(__fmul_rn(dx, dx), __fmul_rn(dy, dy));
            acc = __fadd_rn(acc, sqrtf(s));          // HIP default: correctly-rounded sqrt
        }
    }
    float q = __fdiv_rn(acc, 81.0f);
    vote[p] = __fsub_rn(-q, 1.0f);
}

// ---------------- K3: 7x7 max pool, keep mask, center_map, candidate compaction ----------------
__global__ __launch_bounds__(256) void k_pool(const float* __restrict__ vote,
                                              float* __restrict__ cmap_out,
                                              float* __restrict__ cscore,
                                              int* __restrict__ cidx,
                                              int* __restrict__ ccnt,
                                              float thr_keep) {
    int p = blockIdx.x * 256 + threadIdx.x;
    if (p >= NB * HWSZ) return;
    int b = p >> 19;
    int pix = p & (HWSZ - 1);
    int y = pix >> 10;
    int x = pix & (NW - 1);
    const float* vb = vote + (size_t)b * HWSZ;
    float v = vb[pix];
    float mx = -INFINITY;
#pragma unroll
    for (int dy = -3; dy <= 3; dy++) {
        int yy = y + dy;
        if (yy < 0 || yy >= NH) continue;
#pragma unroll
        for (int dx = -3; dx <= 3; dx++) {
            int xx = x + dx;
            if (xx < 0 || xx >= NW) continue;
            float w = vb[yy * NW + xx];
            mx = fmaxf(mx, w);
        }
    }
    bool keep = (mx == v) && (v > thr_keep);
    cmap_out[p] = keep ? v : 0.0f;
    if (keep) {
        int pos = atomicAdd(&ccnt[b], 1);
        if (pos < CAPC) {
            cscore[b * CAPC + pos] = v;
            cidx[b * CAPC + pos] = pix;
        }
    }
}

// ---------------- K4: top-200 selection, one block per batch ----------------
__global__ __launch_bounds__(256) void k_topk(float* __restrict__ cscore,
                                              const int* __restrict__ cidx,
                                              const int* __restrict__ ccnt,
                                              float* __restrict__ cxArr,
                                              float* __restrict__ cyArr,
                                              float* __restrict__ out_centers,
                                              float* __restrict__ out_topvals) {
    __shared__ float sv[STAGE];
    __shared__ int   si[STAGE];
    __shared__ float rv[256];
    __shared__ int   ri[256];
    __shared__ int   rp[256];
    __shared__ float s_tv[TK];
    __shared__ int   s_ti[TK];
    int b = blockIdx.x;
    int tid = threadIdx.x;
    int n = ccnt[b];
    if (n > CAPC) n = CAPC;
    bool staged = (n <= STAGE);
    float* gs = cscore + (size_t)b * CAPC;
    const int* gi = cidx + (size_t)b * CAPC;
    if (staged) {
        for (int c = tid; c < n; c += 256) { sv[c] = gs[c]; si[c] = gi[c]; }
    }
    __syncthreads();
    for (int k = 0; k < TK; k++) {
        float bv = -INFINITY; int bi = 0x7fffffff; int bp = -1;
        for (int c = tid; c < n; c += 256) {
            float v; int idx;
            if (staged) { v = sv[c]; idx = si[c]; }
            else        { v = gs[c]; idx = gi[c]; }
            if (v > bv || (v == bv && idx < bi)) { bv = v; bi = idx; bp = c; }
        }
        rv[tid] = bv; ri[tid] = bi; rp[tid] = bp;
        __syncthreads();
        for (int s = 128; s > 0; s >>= 1) {
            if (tid < s) {
                float v2 = rv[tid + s]; int i2 = ri[tid + s];
                if (v2 > rv[tid] || (v2 == rv[tid] && i2 < ri[tid])) {
                    rv[tid] = v2; ri[tid] = i2; rp[tid] = rp[tid + s];
                }
            }
            __syncthreads();
        }
        if (tid == 0) {
            s_tv[k] = rv[0]; s_ti[k] = ri[0];
            if (rp[0] >= 0) {
                if (staged) sv[rp[0]] = -INFINITY;
                else        gs[rp[0]] = -INFINITY;
            }
        }
        __syncthreads();
    }
    if (tid < TK) {
        float v = s_tv[tid];
        int idx = s_ti[tid];
        int ys = idx >> 10;
        int xs = idx & (NW - 1);
        bool valid = (v != -INFINITY);
        cxArr[b * TK + tid] = valid ? (float)xs : 1e9f;
        cyArr[b * TK + tid] = valid ? (float)ys : 1e9f;
        out_centers[(b * TK + tid) * 2 + 0] = (float)ys;
        out_centers[(b * TK + tid) * 2 + 1] = (float)xs;
        out_topvals[b * TK + tid] = v;
    }
}

// ---------------- K5: instance assignment (argmin over 200 centers) + seg_counts ----------------
__global__ __launch_bounds__(256) void k_assign(const float* __restrict__ reg,
                                                const int* __restrict__ segid,
                                                const float* __restrict__ cxArr,
                                                const float* __restrict__ cyArr,
                                                float* __restrict__ out_inst,
                                                int* __restrict__ instid,
                                                int* __restrict__ segcnt) {
    __shared__ float scx[TK];
    __shared__ float scy[TK];
    int tid = threadIdx.x;
    int p = blockIdx.x * 256 + tid;
    int b = p >> 19;                       // whole block shares b (HWSZ/256 = 2048 blocks/batch)
    int pix = p & (HWSZ - 1);
    if (tid < TK) {
        scx[tid] = cxArr[b * TK + tid];
        scy[tid] = cyArr[b * TK + tid];
    }
    __syncthreads();
    if (p >= NB * HWSZ) return;
    int y = pix >> 10;
    int x = pix & (NW - 1);
    const float* r0 = reg + (size_t)b * 2 * HWSZ;
    const float* r1 = r0 + HWSZ;
    float px = __fsub_rn((float)(x + 1), r0[pix]);
    float py = __fsub_rn((float)(y + 1), r1[pix]);
    float bd = INFINITY; int bk = 0;
#pragma unroll 8
    for (int k = 0; k < TK; k++) {
        float dx = __fsub_rn(px, scx[k]);
        float dy = __fsub_rn(py, scy[k]);
        float d2 = __fadd_rn(__fmul_rn(dx, dx), __fmul_rn(dy, dy));
        if (d2 < bd) { bd = d2; bk = k; }
    }
    int cls = segid[p];
    int thing = (cls >= 24) ? 1 : 0;
    int inst = (bk + 1) * thing;
    out_inst[p] = (float)inst;
    instid[p] = inst;
    if (inst > 0) atomicAdd(&segcnt[(b * TK + bk) * NC + cls], 1);
}

// ---------------- K6: per-instance class argmax + size ----------------
__global__ __launch_bounds__(256) void k_stats(const int* __restrict__ segcnt,
                                               float* __restrict__ out_icls,
                                               float* __restrict__ out_isize,
                                               int* __restrict__ icls,
                                               int* __restrict__ isize) {
    int t = blockIdx.x * 256 + threadIdx.x;
    if (t >= NB * TK) return;
    const int* row = segcnt + (size_t)t * NC;
    int total = 0; int bc = 0; int bv = -1;
#pragma unroll
    for (int c = 0; c < NC; c++) {
        int v = row[c];
        total += v;
        if (v > bv) { bv = v; bc = c; }
    }
    out_icls[t] = (float)bc;
    out_isize[t] = (float)total;
    icls[t] = bc;
    isize[t] = total;
}

// ---------------- K7: prob sum of selected class per instance ----------------
__global__ __launch_bounds__(256) void k_probsum(const float* __restrict__ logits,
                                                 const int* __restrict__ instid,
                                                 const float* __restrict__ mArr,
                                                 const float* __restrict__ dArr,
                                                 const int* __restrict__ icls,
                                                 float* __restrict__ probsum) {
    int p = blockIdx.x * 256 + threadIdx.x;
    if (p >= NB * HWSZ) return;
    int inst = instid[p];
    if (inst == 0) return;
    int b = p >> 19;
    int pix = p & (HWSZ - 1);
    int c = icls[b * TK + inst - 1];
    float xv = logits[(size_t)(b * NC + c) * HWSZ + pix];
    float pr = __fdiv_rn(expf(__fsub_rn(xv, mArr[p])), dArr[p]);
    atomicAdd(&probsum[b * TK + inst - 1], pr);
}

// ---------------- K8: finalize inst_seg_prob ----------------
__global__ __launch_bounds__(256) void k_final(const float* __restrict__ probsum,
                                               const int* __restrict__ isize,
                                               float* __restrict__ out_iprob) {
    int t = blockIdx.x * 256 + threadIdx.x;
    if (t >= NB * TK) return;
    float s = probsum[t];
    float sz = (float)isize[t];
    out_iprob[t] = __fdiv_rn(s, fmaxf(sz, 1.0f));
}

// ---------------- K0: zero accumulators ----------------
__global__ __launch_bounds__(256) void k_zero(int* __restrict__ ccnt,
                                              int* __restrict__ segcnt,
                                              float* __restrict__ probsum) {
    int t = blockIdx.x * 256 + threadIdx.x;
    if (t < NB) ccnt[t] = 0;
    if (t < NB * TK * NC) segcnt[t] = 0;
    if (t < NB * TK) probsum[t] = 0.f;
}

// Host: replicate _circle_constants threshold exactly (NumPy pairwise sum, f32)
static float compute_thr_keep() {
    float cdm[121];
    int t = 0;
    for (int i = 0; i < 11; i++) {
        for (int j = 0; j < 11; j++) {
            float ox = (float)(j - 5), oy = (float)(i - 5);
            float cd = sqrtf(ox * ox + oy * oy);   // exact int inputs -> correctly rounded
            float cm = (cd <= 5.0f) ? 1.0f : 0.0f;
            cdm[t++] = cd * cm;
        }
    }
    // NumPy pairwise_sum for n=121 (<=128): 8 accumulators + remainder
    float r[8];
    for (int k = 0; k < 8; k++) r[k] = cdm[k];
    int i = 8;
    for (; i < 121 - (121 % 8); i += 8)
        for (int k = 0; k < 8; k++) r[k] += cdm[i + k];
    float res = ((r[0] + r[1]) + (r[2] + r[3])) + ((r[4] + r[5]) + (r[6] + r[7]));
    for (; i < 121; i++) res += cdm[i];
    float thr = res / 81.0f;                       // np.float32 / python float -> f32
    double kt = -(double)thr - 1.0;                // python double expression
    return (float)kt;                              // weak cast to f32 in jnp comparison
}

extern "C" void kernel_launch(void* const* d_in, const int* in_sizes, int n_in,
                              void* d_out, int out_size, void* d_ws, size_t ws_size,
                              hipStream_t stream) {
    const float* logits = (const float*)d_in[0];
    const float* reg    = (const float*)d_in[2];
    float* out = (float*)d_out;

    // output layout (all f32)
    float* o_inst    = out;                       // B*HW
    float* o_seg     = out + 1048576;             // B*HW
    float* o_centers = out + 2097152;             // B*TK*2
    float* o_topvals = out + 2097952;             // B*TK
    float* o_icls    = out + 2098352;             // B*TK
    float* o_iprob   = out + 2098752;             // B*TK
    float* o_isize   = out + 2099152;             // B*TK
    float* o_cmap    = out + 2099552;             // B*HW

    // workspace layout (4B units)
    float* wsf = (float*)d_ws;
    size_t o = 0;
    float* vote   = wsf + o; o += (size_t)NB * HWSZ;
    float* mArr   = wsf + o; o += (size_t)NB * HWSZ;
    float* dArr   = wsf + o; o += (size_t)NB * HWSZ;
    int*   segid  = (int*)(wsf + o); o += (size_t)NB * HWSZ;
    int*   instid = (int*)(wsf + o); o += (size_t)NB * HWSZ;
    float* cscore = wsf + o; o += (size_t)NB * CAPC;
    int*   cidx   = (int*)(wsf + o); o += (size_t)NB * CAPC;
    int*   ccnt   = (int*)(wsf + o); o += 8;
    float* cxArr  = wsf + o; o += NB * TK;
    float* cyArr  = wsf + o; o += NB * TK;
    int*   segcnt = (int*)(wsf + o); o += (size_t)NB * TK * NC;
    float* probsum= wsf + o; o += NB * TK;
    int*   icls   = (int*)(wsf + o); o += NB * TK;
    int*   isize  = (int*)(wsf + o); o += NB * TK;

    float thr_keep = compute_thr_keep();

    int gridPix = (NB * HWSZ) / 256;   // 4096

    k_zero<<<(NB * TK * NC + 255) / 256, 256, 0, stream>>>(ccnt, segcnt, probsum);
    k_seg<<<gridPix, 256, 0, stream>>>(logits, o_seg, segid, mArr, dArr);
    k_vote<<<gridPix, 256, 0, stream>>>(reg, vote);
    k_pool<<<gridPix, 256, 0, stream>>>(vote, o_cmap, cscore, cidx, ccnt, thr_keep);
    k_topk<<<NB, 256, 0, stream>>>(cscore, cidx, ccnt, cxArr, cyArr, o_centers, o_topvals);
    k_assign<<<gridPix, 256, 0, stream>>>(reg, segid, cxArr, cyArr, o_inst, instid, segcnt);
    k_stats<<<(NB * TK + 255) / 256, 256, 0, stream>>>(segcnt, o_icls, o_isize, icls, isize);
    k_probsum<<<gridPix, 256, 0, stream>>>(logits, instid, mArr, dArr, icls, probsum);
    k_final<<<(NB * TK + 255) / 256, 256, 0, stream>>>(probsum, isize, o_iprob);
}

// Round 2
// 979.572 us; speedup vs baseline: 1.3965x; 1.3965x over previous
//
#include <hip/hip_runtime.h>
#include <cfloat>
#include <cmath>

#define NB 2
#define NC 34
#define NH 512
#define NW 1024
#define HWSZ (NH*NW)          // 524288 = 2^19
#define TK 200
#define CAPC 49152            // >= plausible 7x7 local-maxima count
#define STAGE 6144            // LDS staging capacity for top-k keys (48KB)

typedef unsigned long long u64;

__device__ inline u64 shfl_xor_u64(u64 v, int mask) {
    return (u64)__shfl_xor((long long)v, mask, 64);
}

// ---------------- K1: softmax argmax + max + denom ----------------
__global__ __launch_bounds__(256) void k_seg(const float* __restrict__ logits,
                                             float* __restrict__ segmap_out,
                                             int* __restrict__ segid,
                                             float* __restrict__ mArr,
                                             float* __restrict__ dArr) {
    int p = blockIdx.x * 256 + threadIdx.x;
    if (p >= NB * HWSZ) return;
    int b = p >> 19;
    int pix = p & (HWSZ - 1);
    const float* base = logits + (size_t)b * NC * HWSZ + pix;
    float v[NC];
#pragma unroll
    for (int c = 0; c < NC; c++) v[c] = base[(size_t)c * HWSZ];
    float m = -FLT_MAX; int bc = 0;
#pragma unroll
    for (int c = 0; c < NC; c++) { if (v[c] > m) { m = v[c]; bc = c; } }
    float den = 0.f;
#pragma unroll
    for (int c = 0; c < NC; c++) den += expf(v[c] - m);
    segmap_out[p] = (float)bc;
    segid[p] = bc;
    mArr[p] = m;
    dArr[p] = den;
}

// ---------------- K2: vote map (exact f32 order as reference) ----------------
__global__ __launch_bounds__(256) void k_vote(const float* __restrict__ reg,
                                              float* __restrict__ vote) {
    int p = blockIdx.x * 256 + threadIdx.x;
    if (p >= NB * HWSZ) return;
    int b = p >> 19;
    int pix = p & (HWSZ - 1);
    int y = pix >> 10;
    int x = pix & (NW - 1);
    const float* r0 = reg + (size_t)b * 2 * HWSZ;
    const float* r1 = r0 + HWSZ;
    float acc = 0.f;
#pragma unroll
    for (int i = 0; i < 11; i++) {
        int di = i - 5;
        int yy = y + di;
#pragma unroll
        for (int j = 0; j < 11; j++) {
            int dj = j - 5;
            if (di * di + dj * dj > 25) continue;   // cmask, exact integer test
            int xx = x + dj;
            bool in = (yy >= 0) && (yy < NH) && (xx >= 0) && (xx < NW);
            float rx = 0.f, ry = 0.f;
            if (in) {
                int q = yy * NW + xx;
                rx = r0[q];
                ry = r1[q];
            }
            float dx = __fsub_rn((float)dj, rx);
            float dy = __fsub_rn((float)di, ry);
            float s  = __fadd_rn(__fmul_rn(dx, dx), __fmul_rn(dy, dy));
            acc = __fadd_rn(acc, sqrtf(s));          // correctly-rounded sqrt
        }
    }
    float q = __fdiv_rn(acc, 81.0f);
    vote[p] = __fsub_rn(-q, 1.0f);
}

// ---------------- K3: 7x7 max pool, keep mask, center_map, key compaction ----------------
__global__ __launch_bounds__(256) void k_pool(const float* __restrict__ vote,
                                              float* __restrict__ cmap_out,
                                              u64* __restrict__ keys,
                                              int* __restrict__ ccnt,
                                              float thr_keep) {
    int p = blockIdx.x * 256 + threadIdx.x;
    if (p >= NB * HWSZ) return;
    int b = p >> 19;
    int pix = p & (HWSZ - 1);
    int y = pix >> 10;
    int x = pix & (NW - 1);
    const float* vb = vote + (size_t)b * HWSZ;
    float v = vb[pix];
    float mx = -INFINITY;
#pragma unroll
    for (int dy = -3; dy <= 3; dy++) {
        int yy = y + dy;
        if (yy < 0 || yy >= NH) continue;
#pragma unroll
        for (int dx = -3; dx <= 3; dx++) {
            int xx = x + dx;
            if (xx < 0 || xx >= NW) continue;
            float w = vb[yy * NW + xx];
            mx = fmaxf(mx, w);
        }
    }
    bool keep = (mx == v) && (v > thr_keep);
    cmap_out[p] = keep ? v : 0.0f;
    if (keep) {
        int pos = atomicAdd(&ccnt[b], 1);
        if (pos < CAPC) {
            unsigned u = __float_as_uint(v);
            unsigned ou = ((int)u < 0) ? ~u : (u | 0x80000000u);  // order-preserving map
            // key: value desc, then index asc; key==0 reserved as sentinel
            keys[(size_t)b * CAPC + pos] = ((u64)ou << 19) | (u64)(HWSZ - 1 - pix);
        }
    }
}

// ---------------- K4: single-wave tournament top-200 ----------------
__global__ __launch_bounds__(64) void k_topk(u64* __restrict__ keys_g,
                                             const int* __restrict__ ccnt,
                                             float* __restrict__ cxArr,
                                             float* __restrict__ cyArr,
                                             float* __restrict__ out_centers,
                                             float* __restrict__ out_topvals) {
    __shared__ u64 sk[STAGE];
    __shared__ u64 s_out[TK];
    int b = blockIdx.x;
    int lane = threadIdx.x;
    int n = ccnt[b];
    if (n > CAPC) n = CAPC;
    u64* Kg = keys_g + (size_t)b * CAPC;
    bool staged = (n <= STAGE);
    u64* K = staged ? sk : Kg;
    if (staged) {
        for (int c = lane; c < n; c += 64) sk[c] = Kg[c];
    }
    __syncthreads();
    int m = (n + 63) >> 6;          // segment length per lane
    int lo = lane * m;
    int hi = lo + m; if (hi > n) hi = n;
    u64 best = 0;
    for (int c = lo; c < hi; c++) { u64 kv = K[c]; if (kv > best) best = kv; }

    for (int k = 0; k < TK; k++) {
        // wave argmax over segment maxima (6-step butterfly, no barriers)
        u64 w = best;
#pragma unroll
        for (int off = 32; off; off >>= 1) {
            u64 o = shfl_xor_u64(w, off);
            if (o > w) w = o;
        }
        if (lane == 0) s_out[k] = w;
        u64 bal = __ballot(best == w && w != 0ULL);
        if (bal) {
            int wl = (int)(__ffsll((long long)bal) - 1);   // unique winner (keys unique)
            int wlo = wl * m;
            int whi = wlo + m; if (whi > n) whi = n;
            // all 64 lanes rescan winner's segment: remove w, recompute its max
            u64 part = 0;
            for (int c = wlo + lane; c < whi; c += 64) {
                u64 kv = K[c];
                if (kv == w) { K[c] = 0; kv = 0; }
                if (kv > part) part = kv;
            }
#pragma unroll
            for (int off = 32; off; off >>= 1) {
                u64 o = shfl_xor_u64(part, off);
                if (o > part) part = o;
            }
            if (lane == wl) best = part;
        }
        __syncthreads();   // 1 wave: near-free; orders the LDS/global removal write
    }

    for (int t = lane; t < TK; t += 64) {
        u64 w = s_out[t];
        bool valid = (w != 0ULL);
        unsigned ou = (unsigned)(w >> 19);
        unsigned ub = (ou & 0x80000000u) ? (ou & 0x7FFFFFFFu) : ~ou;
        float v = __uint_as_float(ub);
        int pix = valid ? (int)(HWSZ - 1 - (int)(w & 0x7FFFFULL)) : 0x7fffffff;
        int ys = pix >> 10;
        int xs = pix & (NW - 1);
        cxArr[b * TK + t] = valid ? (float)xs : 1e9f;
        cyArr[b * TK + t] = valid ? (float)ys : 1e9f;
        out_centers[(b * TK + t) * 2 + 0] = (float)ys;
        out_centers[(b * TK + t) * 2 + 1] = (float)xs;
        out_topvals[b * TK + t] = valid ? v : -INFINITY;
    }
}

// ---------------- K5: instance assignment (argmin over 200 centers) + seg_counts ----------------
__global__ __launch_bounds__(256) void k_assign(const float* __restrict__ reg,
                                                const int* __restrict__ segid,
                                                const float* __restrict__ cxArr,
                                                const float* __restrict__ cyArr,
                                                float* __restrict__ out_inst,
                                                int* __restrict__ instid,
                                                int* __restrict__ segcnt) {
    __shared__ float scx[TK];
    __shared__ float scy[TK];
    int tid = threadIdx.x;
    int p = blockIdx.x * 256 + tid;
    int b = p >> 19;                       // whole block shares b
    int pix = p & (HWSZ - 1);
    if (tid < TK) {
        scx[tid] = cxArr[b * TK + tid];
        scy[tid] = cyArr[b * TK + tid];
    }
    __syncthreads();
    if (p >= NB * HWSZ) return;
    int y = pix >> 10;
    int x = pix & (NW - 1);
    const float* r0 = reg + (size_t)b * 2 * HWSZ;
    const float* r1 = r0 + HWSZ;
    float px = __fsub_rn((float)(x + 1), r0[pix]);
    float py = __fsub_rn((float)(y + 1), r1[pix]);
    float bd = INFINITY; int bk = 0;
#pragma unroll 8
    for (int k = 0; k < TK; k++) {
        float dx = __fsub_rn(px, scx[k]);
        float dy = __fsub_rn(py, scy[k]);
        float d2 = __fadd_rn(__fmul_rn(dx, dx), __fmul_rn(dy, dy));
        if (d2 < bd) { bd = d2; bk = k; }
    }
    int cls = segid[p];
    int thing = (cls >= 24) ? 1 : 0;
    int inst = (bk + 1) * thing;
    out_inst[p] = (float)inst;
    instid[p] = inst;
    if (inst > 0) atomicAdd(&segcnt[(b * TK + bk) * NC + cls], 1);
}

// ---------------- K6: per-instance class argmax + size ----------------
__global__ __launch_bounds__(256) void k_stats(const int* __restrict__ segcnt,
                                               float* __restrict__ out_icls,
                                               float* __restrict__ out_isize,
                                               int* __restrict__ icls,
                                               int* __restrict__ isize) {
    int t = blockIdx.x * 256 + threadIdx.x;
    if (t >= NB * TK) return;
    const int* row = segcnt + (size_t)t * NC;
    int total = 0; int bc = 0; int bv = -1;
#pragma unroll
    for (int c = 0; c < NC; c++) {
        int v = row[c];
        total += v;
        if (v > bv) { bv = v; bc = c; }
    }
    out_icls[t] = (float)bc;
    out_isize[t] = (float)total;
    icls[t] = bc;
    isize[t] = total;
}

// ---------------- K7: prob sum of selected class per instance ----------------
__global__ __launch_bounds__(256) void k_probsum(const float* __restrict__ logits,
                                                 const int* __restrict__ instid,
                                                 const float* __restrict__ mArr,
                                                 const float* __restrict__ dArr,
                                                 const int* __restrict__ icls,
                                                 float* __restrict__ probsum) {
    int p = blockIdx.x * 256 + threadIdx.x;
    if (p >= NB * HWSZ) return;
    int inst = instid[p];
    if (inst == 0) return;
    int b = p >> 19;
    int pix = p & (HWSZ - 1);
    int c = icls[b * TK + inst - 1];
    float xv = logits[(size_t)(b * NC + c) * HWSZ + pix];
    float pr = __fdiv_rn(expf(__fsub_rn(xv, mArr[p])), dArr[p]);
    atomicAdd(&probsum[b * TK + inst - 1], pr);
}

// ---------------- K8: finalize inst_seg_prob ----------------
__global__ __launch_bounds__(256) void k_final(const float* __restrict__ probsum,
                                               const int* __restrict__ isize,
                                               float* __restrict__ out_iprob) {
    int t = blockIdx.x * 256 + threadIdx.x;
    if (t >= NB * TK) return;
    float s = probsum[t];
    float sz = (float)isize[t];
    out_iprob[t] = __fdiv_rn(s, fmaxf(sz, 1.0f));
}

// ---------------- K0: zero accumulators ----------------
__global__ __launch_bounds__(256) void k_zero(int* __restrict__ ccnt,
                                              int* __restrict__ segcnt,
                                              float* __restrict__ probsum) {
    int t = blockIdx.x * 256 + threadIdx.x;
    if (t < NB) ccnt[t] = 0;
    if (t < NB * TK * NC) segcnt[t] = 0;
    if (t < NB * TK) probsum[t] = 0.f;
}

// Host: replicate _circle_constants threshold exactly (NumPy pairwise sum, f32)
static float compute_thr_keep() {
    float cdm[121];
    int t = 0;
    for (int i = 0; i < 11; i++) {
        for (int j = 0; j < 11; j++) {
            float ox = (float)(j - 5), oy = (float)(i - 5);
            float cd = sqrtf(ox * ox + oy * oy);
            float cm = (cd <= 5.0f) ? 1.0f : 0.0f;
            cdm[t++] = cd * cm;
        }
    }
    float r[8];
    for (int k = 0; k < 8; k++) r[k] = cdm[k];
    int i = 8;
    for (; i < 121 - (121 % 8); i += 8)
        for (int k = 0; k < 8; k++) r[k] += cdm[i + k];
    float res = ((r[0] + r[1]) + (r[2] + r[3])) + ((r[4] + r[5]) + (r[6] + r[7]));
    for (; i < 121; i++) res += cdm[i];
    float thr = res / 81.0f;
    double kt = -(double)thr - 1.0;
    return (float)kt;
}

extern "C" void kernel_launch(void* const* d_in, const int* in_sizes, int n_in,
                              void* d_out, int out_size, void* d_ws, size_t ws_size,
                              hipStream_t stream) {
    const float* logits = (const float*)d_in[0];
    const float* reg    = (const float*)d_in[2];
    float* out = (float*)d_out;

    // output layout (all f32)
    float* o_inst    = out;                       // B*HW
    float* o_seg     = out + 1048576;             // B*HW
    float* o_centers = out + 2097152;             // B*TK*2
    float* o_topvals = out + 2097952;             // B*TK
    float* o_icls    = out + 2098352;             // B*TK
    float* o_iprob   = out + 2098752;             // B*TK
    float* o_isize   = out + 2099152;             // B*TK
    float* o_cmap    = out + 2099552;             // B*HW

    // workspace layout: keys first (8B-aligned), then 4B arrays
    u64* keys = (u64*)d_ws;                                   // NB*CAPC
    float* wsf = (float*)(keys + (size_t)NB * CAPC);
    size_t o = 0;
    float* vote   = wsf + o; o += (size_t)NB * HWSZ;
    float* mArr   = wsf + o; o += (size_t)NB * HWSZ;
    float* dArr   = wsf + o; o += (size_t)NB * HWSZ;
    int*   segid  = (int*)(wsf + o); o += (size_t)NB * HWSZ;
    int*   instid = (int*)(wsf + o); o += (size_t)NB * HWSZ;
    int*   ccnt   = (int*)(wsf + o); o += 8;
    float* cxArr  = wsf + o; o += NB * TK;
    float* cyArr  = wsf + o; o += NB * TK;
    int*   segcnt = (int*)(wsf + o); o += (size_t)NB * TK * NC;
    float* probsum= wsf + o; o += NB * TK;
    int*   icls   = (int*)(wsf + o); o += NB * TK;
    int*   isize  = (int*)(wsf + o); o += NB * TK;

    float thr_keep = compute_thr_keep();

    int gridPix = (NB * HWSZ) / 256;   // 4096

    k_zero<<<(NB * TK * NC + 255) / 256, 256, 0, stream>>>(ccnt, segcnt, probsum);
    k_seg<<<gridPix, 256, 0, stream>>>(logits, o_seg, segid, mArr, dArr);
    k_vote<<<gridPix, 256, 0, stream>>>(reg, vote);
    k_pool<<<gridPix, 256, 0, stream>>>(vote, o_cmap, keys, ccnt, thr_keep);
    k_topk<<<NB, 64, 0, stream>>>(keys, ccnt, cxArr, cyArr, o_centers, o_topvals);
    k_assign<<<gridPix, 256, 0, stream>>>(reg, segid, cxArr, cyArr, o_inst, instid, segcnt);
    k_stats<<<(NB * TK + 255) / 256, 256, 0, stream>>>(segcnt, o_icls, o_isize, icls, isize);
    k_probsum<<<gridPix, 256, 0, stream>>>(logits, instid, mArr, dArr, icls, probsum);
    k_final<<<(NB * TK + 255) / 256, 256, 0, stream>>>(probsum, isize, o_iprob);
}

// Round 3
// 560.589 us; speedup vs baseline: 2.4402x; 1.7474x over previous
//
#include <hip/hip_runtime.h>
#include <cfloat>
#include <cmath>

#define NB 2
#define NC 34
#define NH 512
#define NW 1024
#define HWSZ (NH*NW)          // 524288 = 2^19
#define TK 200
#define CAPC 49152            // >= plausible 7x7 local-maxima count
#define STAGE 6144            // LDS staging capacity for top-k keys (48KB)
#define ACH 1024              // pixels per block for aggregation kernels

typedef unsigned long long u64;

__device__ inline u64 shfl_xor_u64(u64 v, int mask) {
    return (u64)__shfl_xor((long long)v, mask, 64);
}

// ---------------- K1: softmax argmax + max + denom ----------------
__global__ __launch_bounds__(256) void k_seg(const float* __restrict__ logits,
                                             float* __restrict__ segmap_out,
                                             int* __restrict__ segid,
                                             float* __restrict__ mArr,
                                             float* __restrict__ dArr) {
    int p = blockIdx.x * 256 + threadIdx.x;
    if (p >= NB * HWSZ) return;
    int b = p >> 19;
    int pix = p & (HWSZ - 1);
    const float* base = logits + (size_t)b * NC * HWSZ + pix;
    float v[NC];
#pragma unroll
    for (int c = 0; c < NC; c++) v[c] = base[(size_t)c * HWSZ];
    float m = -FLT_MAX; int bc = 0;
#pragma unroll
    for (int c = 0; c < NC; c++) { if (v[c] > m) { m = v[c]; bc = c; } }
    float den = 0.f;
#pragma unroll
    for (int c = 0; c < NC; c++) den += expf(v[c] - m);
    segmap_out[p] = (float)bc;
    segid[p] = bc;
    mArr[p] = m;
    dArr[p] = den;
}

// ---------------- K2: vote map (exact f32 order as reference) ----------------
__global__ __launch_bounds__(256) void k_vote(const float* __restrict__ reg,
                                              float* __restrict__ vote) {
    int p = blockIdx.x * 256 + threadIdx.x;
    if (p >= NB * HWSZ) return;
    int b = p >> 19;
    int pix = p & (HWSZ - 1);
    int y = pix >> 10;
    int x = pix & (NW - 1);
    const float* r0 = reg + (size_t)b * 2 * HWSZ;
    const float* r1 = r0 + HWSZ;
    float acc = 0.f;
#pragma unroll
    for (int i = 0; i < 11; i++) {
        int di = i - 5;
        int yy = y + di;
#pragma unroll
        for (int j = 0; j < 11; j++) {
            int dj = j - 5;
            if (di * di + dj * dj > 25) continue;   // cmask, exact integer test
            int xx = x + dj;
            bool in = (yy >= 0) && (yy < NH) && (xx >= 0) && (xx < NW);
            float rx = 0.f, ry = 0.f;
            if (in) {
                int q = yy * NW + xx;
                rx = r0[q];
                ry = r1[q];
            }
            float dx = __fsub_rn((float)dj, rx);
            float dy = __fsub_rn((float)di, ry);
            float s  = __fadd_rn(__fmul_rn(dx, dx), __fmul_rn(dy, dy));
            acc = __fadd_rn(acc, sqrtf(s));          // correctly-rounded sqrt
        }
    }
    float q = __fdiv_rn(acc, 81.0f);
    vote[p] = __fsub_rn(-q, 1.0f);
}

// ---------------- K3: 7x7 max pool, keep mask, center_map, key compaction ----------------
__global__ __launch_bounds__(256) void k_pool(const float* __restrict__ vote,
                                              float* __restrict__ cmap_out,
                                              u64* __restrict__ keys,
                                              int* __restrict__ ccnt,
                                              float thr_keep) {
    int p = blockIdx.x * 256 + threadIdx.x;
    if (p >= NB * HWSZ) return;
    int b = p >> 19;
    int pix = p & (HWSZ - 1);
    int y = pix >> 10;
    int x = pix & (NW - 1);
    const float* vb = vote + (size_t)b * HWSZ;
    float v = vb[pix];
    float mx = -INFINITY;
#pragma unroll
    for (int dy = -3; dy <= 3; dy++) {
        int yy = y + dy;
        if (yy < 0 || yy >= NH) continue;
#pragma unroll
        for (int dx = -3; dx <= 3; dx++) {
            int xx = x + dx;
            if (xx < 0 || xx >= NW) continue;
            float w = vb[yy * NW + xx];
            mx = fmaxf(mx, w);
        }
    }
    bool keep = (mx == v) && (v > thr_keep);
    cmap_out[p] = keep ? v : 0.0f;
    if (keep) {
        int pos = atomicAdd(&ccnt[b], 1);
        if (pos < CAPC) {
            unsigned u = __float_as_uint(v);
            unsigned ou = ((int)u < 0) ? ~u : (u | 0x80000000u);  // order-preserving map
            // key: value desc, then index asc; key==0 reserved as sentinel
            keys[(size_t)b * CAPC + pos] = ((u64)ou << 19) | (u64)(HWSZ - 1 - pix);
        }
    }
}

// ---------------- K4: single-wave tournament top-200 ----------------
__global__ __launch_bounds__(64) void k_topk(u64* __restrict__ keys_g,
                                             const int* __restrict__ ccnt,
                                             float* __restrict__ cxArr,
                                             float* __restrict__ cyArr,
                                             float* __restrict__ out_centers,
                                             float* __restrict__ out_topvals) {
    __shared__ u64 sk[STAGE];
    __shared__ u64 s_out[TK];
    int b = blockIdx.x;
    int lane = threadIdx.x;
    int n = ccnt[b];
    if (n > CAPC) n = CAPC;
    u64* Kg = keys_g + (size_t)b * CAPC;
    bool staged = (n <= STAGE);
    u64* K = staged ? sk : Kg;
    if (staged) {
        for (int c = lane; c < n; c += 64) sk[c] = Kg[c];
    }
    __syncthreads();
    int m = (n + 63) >> 6;          // segment length per lane
    int lo = lane * m;
    int hi = lo + m; if (hi > n) hi = n;
    u64 best = 0;
    for (int c = lo; c < hi; c++) { u64 kv = K[c]; if (kv > best) best = kv; }

    for (int k = 0; k < TK; k++) {
        u64 w = best;
#pragma unroll
        for (int off = 32; off; off >>= 1) {
            u64 o = shfl_xor_u64(w, off);
            if (o > w) w = o;
        }
        if (lane == 0) s_out[k] = w;
        u64 bal = __ballot(best == w && w != 0ULL);
        if (bal) {
            int wl = (int)(__ffsll((long long)bal) - 1);   // unique winner (keys unique)
            int wlo = wl * m;
            int whi = wlo + m; if (whi > n) whi = n;
            u64 part = 0;
            for (int c = wlo + lane; c < whi; c += 64) {
                u64 kv = K[c];
                if (kv == w) { K[c] = 0; kv = 0; }
                if (kv > part) part = kv;
            }
#pragma unroll
            for (int off = 32; off; off >>= 1) {
                u64 o = shfl_xor_u64(part, off);
                if (o > part) part = o;
            }
            if (lane == wl) best = part;
        }
        __syncthreads();
    }

    for (int t = lane; t < TK; t += 64) {
        u64 w = s_out[t];
        bool valid = (w != 0ULL);
        unsigned ou = (unsigned)(w >> 19);
        unsigned ub = (ou & 0x80000000u) ? (ou & 0x7FFFFFFFu) : ~ou;
        float v = __uint_as_float(ub);
        int pix = valid ? (int)(HWSZ - 1 - (int)(w & 0x7FFFFULL)) : 0x7fffffff;
        int ys = pix >> 10;
        int xs = pix & (NW - 1);
        cxArr[b * TK + t] = valid ? (float)xs : 1e9f;
        cyArr[b * TK + t] = valid ? (float)ys : 1e9f;
        out_centers[(b * TK + t) * 2 + 0] = (float)ys;
        out_centers[(b * TK + t) * 2 + 1] = (float)xs;
        out_topvals[b * TK + t] = valid ? v : -INFINITY;
    }
}

// ---------------- K5: instance assignment + LDS-aggregated seg_counts ----------------
// Each block owns ACH=1024 contiguous pixels (1 row); aggregates seg_counts in
// LDS, flushes only nonzero bins. 4 pixels/thread so scx/scy LDS broadcasts are
// reused 4x in the 200-center argmin.
__global__ __launch_bounds__(256) void k_assign(const float* __restrict__ reg,
                                                const int* __restrict__ segid,
                                                const float* __restrict__ cxArr,
                                                const float* __restrict__ cyArr,
                                                float* __restrict__ out_inst,
                                                int* __restrict__ instid,
                                                int* __restrict__ segcnt) {
    __shared__ float scx[TK];
    __shared__ float scy[TK];
    __shared__ int lcnt[TK * NC];
    int tid = threadIdx.x;
    int base = blockIdx.x * ACH;           // grid = NB*HWSZ/ACH, ACH | HWSZ -> uniform b
    int b = base >> 19;
    if (tid < TK) {
        scx[tid] = cxArr[b * TK + tid];
        scy[tid] = cyArr[b * TK + tid];
    }
    for (int t = tid; t < TK * NC; t += 256) lcnt[t] = 0;
    __syncthreads();
    const float* r0 = reg + (size_t)b * 2 * HWSZ;
    const float* r1 = r0 + HWSZ;
    float px[4], py[4], bd[4];
    int bk[4];
#pragma unroll
    for (int it = 0; it < 4; it++) {
        int pix = (base & (HWSZ - 1)) + it * 256 + tid;
        int y = pix >> 10;
        int x = pix & (NW - 1);
        px[it] = __fsub_rn((float)(x + 1), r0[pix]);
        py[it] = __fsub_rn((float)(y + 1), r1[pix]);
        bd[it] = INFINITY; bk[it] = 0;
    }
#pragma unroll 4
    for (int k = 0; k < TK; k++) {
        float cx = scx[k];
        float cy = scy[k];
#pragma unroll
        for (int it = 0; it < 4; it++) {
            float dx = __fsub_rn(px[it], cx);
            float dy = __fsub_rn(py[it], cy);
            float d2 = __fadd_rn(__fmul_rn(dx, dx), __fmul_rn(dy, dy));
            if (d2 < bd[it]) { bd[it] = d2; bk[it] = k; }
        }
    }
#pragma unroll
    for (int it = 0; it < 4; it++) {
        int p = base + it * 256 + tid;
        int cls = segid[p];
        int thing = (cls >= 24) ? 1 : 0;
        int inst = (bk[it] + 1) * thing;
        out_inst[p] = (float)inst;
        instid[p] = inst;
        if (inst) atomicAdd(&lcnt[bk[it] * NC + cls], 1);
    }
    __syncthreads();
    for (int t = tid; t < TK * NC; t += 256) {
        int v = lcnt[t];
        if (v) atomicAdd(&segcnt[b * TK * NC + t], v);
    }
}

// ---------------- K6: per-instance class argmax + size ----------------
__global__ __launch_bounds__(256) void k_stats(const int* __restrict__ segcnt,
                                               float* __restrict__ out_icls,
                                               float* __restrict__ out_isize,
                                               int* __restrict__ icls,
                                               int* __restrict__ isize) {
    int t = blockIdx.x * 256 + threadIdx.x;
    if (t >= NB * TK) return;
    const int* row = segcnt + (size_t)t * NC;
    int total = 0; int bc = 0; int bv = -1;
#pragma unroll
    for (int c = 0; c < NC; c++) {
        int v = row[c];
        total += v;
        if (v > bv) { bv = v; bc = c; }
    }
    out_icls[t] = (float)bc;
    out_isize[t] = (float)total;
    icls[t] = bc;
    isize[t] = total;
}

// ---------------- K7: prob sum of selected class, LDS-aggregated ----------------
__global__ __launch_bounds__(256) void k_probsum(const float* __restrict__ logits,
                                                 const int* __restrict__ instid,
                                                 const float* __restrict__ mArr,
                                                 const float* __restrict__ dArr,
                                                 const int* __restrict__ icls,
                                                 float* __restrict__ probsum) {
    __shared__ float lps[TK];
    int tid = threadIdx.x;
    int base = blockIdx.x * ACH;
    int b = base >> 19;
    for (int t = tid; t < TK; t += 256) lps[t] = 0.f;
    __syncthreads();
#pragma unroll
    for (int it = 0; it < 4; it++) {
        int p = base + it * 256 + tid;
        int inst = instid[p];
        if (inst) {
            int pix = p & (HWSZ - 1);
            int c = icls[b * TK + inst - 1];
            float xv = logits[(size_t)(b * NC + c) * HWSZ + pix];
            float pr = __fdiv_rn(expf(__fsub_rn(xv, mArr[p])), dArr[p]);
            atomicAdd(&lps[inst - 1], pr);
        }
    }
    __syncthreads();
    for (int t = tid; t < TK; t += 256) {
        float s = lps[t];
        if (s != 0.f) atomicAdd(&probsum[b * TK + t], s);
    }
}

// ---------------- K8: finalize inst_seg_prob ----------------
__global__ __launch_bounds__(256) void k_final(const float* __restrict__ probsum,
                                               const int* __restrict__ isize,
                                               float* __restrict__ out_iprob) {
    int t = blockIdx.x * 256 + threadIdx.x;
    if (t >= NB * TK) return;
    float s = probsum[t];
    float sz = (float)isize[t];
    out_iprob[t] = __fdiv_rn(s, fmaxf(sz, 1.0f));
}

// ---------------- K0: zero accumulators ----------------
__global__ __launch_bounds__(256) void k_zero(int* __restrict__ ccnt,
                                              int* __restrict__ segcnt,
                                              float* __restrict__ probsum) {
    int t = blockIdx.x * 256 + threadIdx.x;
    if (t < NB) ccnt[t] = 0;
    if (t < NB * TK * NC) segcnt[t] = 0;
    if (t < NB * TK) probsum[t] = 0.f;
}

// Host: replicate _circle_constants threshold exactly (NumPy pairwise sum, f32)
static float compute_thr_keep() {
    float cdm[121];
    int t = 0;
    for (int i = 0; i < 11; i++) {
        for (int j = 0; j < 11; j++) {
            float ox = (float)(j - 5), oy = (float)(i - 5);
            float cd = sqrtf(ox * ox + oy * oy);
            float cm = (cd <= 5.0f) ? 1.0f : 0.0f;
            cdm[t++] = cd * cm;
        }
    }
    float r[8];
    for (int k = 0; k < 8; k++) r[k] = cdm[k];
    int i = 8;
    for (; i < 121 - (121 % 8); i += 8)
        for (int k = 0; k < 8; k++) r[k] += cdm[i + k];
    float res = ((r[0] + r[1]) + (r[2] + r[3])) + ((r[4] + r[5]) + (r[6] + r[7]));
    for (; i < 121; i++) res += cdm[i];
    float thr = res / 81.0f;
    double kt = -(double)thr - 1.0;
    return (float)kt;
}

extern "C" void kernel_launch(void* const* d_in, const int* in_sizes, int n_in,
                              void* d_out, int out_size, void* d_ws, size_t ws_size,
                              hipStream_t stream) {
    const float* logits = (const float*)d_in[0];
    const float* reg    = (const float*)d_in[2];
    float* out = (float*)d_out;

    // output layout (all f32)
    float* o_inst    = out;                       // B*HW
    float* o_seg     = out + 1048576;             // B*HW
    float* o_centers = out + 2097152;             // B*TK*2
    float* o_topvals = out + 2097952;             // B*TK
    float* o_icls    = out + 2098352;             // B*TK
    float* o_iprob   = out + 2098752;             // B*TK
    float* o_isize   = out + 2099152;             // B*TK
    float* o_cmap    = out + 2099552;             // B*HW

    // workspace layout: keys first (8B-aligned), then 4B arrays
    u64* keys = (u64*)d_ws;                                   // NB*CAPC
    float* wsf = (float*)(keys + (size_t)NB * CAPC);
    size_t o = 0;
    float* vote   = wsf + o; o += (size_t)NB * HWSZ;
    float* mArr   = wsf + o; o += (size_t)NB * HWSZ;
    float* dArr   = wsf + o; o += (size_t)NB * HWSZ;
    int*   segid  = (int*)(wsf + o); o += (size_t)NB * HWSZ;
    int*   instid = (int*)(wsf + o); o += (size_t)NB * HWSZ;
    int*   ccnt   = (int*)(wsf + o); o += 8;
    float* cxArr  = wsf + o; o += NB * TK;
    float* cyArr  = wsf + o; o += NB * TK;
    int*   segcnt = (int*)(wsf + o); o += (size_t)NB * TK * NC;
    float* probsum= wsf + o; o += NB * TK;
    int*   icls   = (int*)(wsf + o); o += NB * TK;
    int*   isize  = (int*)(wsf + o); o += NB * TK;

    float thr_keep = compute_thr_keep();

    int gridPix = (NB * HWSZ) / 256;   // 4096
    int gridAgg = (NB * HWSZ) / ACH;   // 1024

    k_zero<<<(NB * TK * NC + 255) / 256, 256, 0, stream>>>(ccnt, segcnt, probsum);
    k_seg<<<gridPix, 256, 0, stream>>>(logits, o_seg, segid, mArr, dArr);
    k_vote<<<gridPix, 256, 0, stream>>>(reg, vote);
    k_pool<<<gridPix, 256, 0, stream>>>(vote, o_cmap, keys, ccnt, thr_keep);
    k_topk<<<NB, 64, 0, stream>>>(keys, ccnt, cxArr, cyArr, o_centers, o_topvals);
    k_assign<<<gridAgg, 256, 0, stream>>>(reg, segid, cxArr, cyArr, o_inst, instid, segcnt);
    k_stats<<<(NB * TK + 255) / 256, 256, 0, stream>>>(segcnt, o_icls, o_isize, icls, isize);
    k_probsum<<<gridAgg, 256, 0, stream>>>(logits, instid, mArr, dArr, icls, probsum);
    k_final<<<(NB * TK + 255) / 256, 256, 0, stream>>>(probsum, isize, o_iprob);
}

// Round 4
// 478.234 us; speedup vs baseline: 2.8604x; 1.1722x over previous
//
#include <hip/hip_runtime.h>
#include <cfloat>
#include <cmath>

#define NB 2
#define NC 34
#define NH 512
#define NW 1024
#define HWSZ (NH*NW)          // 524288 = 2^19
#define TK 200
#define CAPC 49152            // >= plausible 7x7 local-maxima count
#define CHUNK 8192            // LDS sort chunk (64KB)
#define ACH 1024              // pixels per block for aggregation kernels

typedef unsigned long long u64;

// ---------------- K1: softmax argmax + max + denom ----------------
__global__ __launch_bounds__(256) void k_seg(const float* __restrict__ logits,
                                             float* __restrict__ segmap_out,
                                             int* __restrict__ segid,
                                             float* __restrict__ mArr,
                                             float* __restrict__ dArr) {
    int p = blockIdx.x * 256 + threadIdx.x;
    if (p >= NB * HWSZ) return;
    int b = p >> 19;
    int pix = p & (HWSZ - 1);
    const float* base = logits + (size_t)b * NC * HWSZ + pix;
    float v[NC];
#pragma unroll
    for (int c = 0; c < NC; c++) v[c] = base[(size_t)c * HWSZ];
    float m = -FLT_MAX; int bc = 0;
#pragma unroll
    for (int c = 0; c < NC; c++) { if (v[c] > m) { m = v[c]; bc = c; } }
    float den = 0.f;
#pragma unroll
    for (int c = 0; c < NC; c++) den += expf(v[c] - m);
    segmap_out[p] = (float)bc;
    segid[p] = bc;
    mArr[p] = m;
    dArr[p] = den;
}

// ---------------- K2: vote map (exact f32 order as reference) ----------------
__global__ __launch_bounds__(256) void k_vote(const float* __restrict__ reg,
                                              float* __restrict__ vote) {
    int p = blockIdx.x * 256 + threadIdx.x;
    if (p >= NB * HWSZ) return;
    int b = p >> 19;
    int pix = p & (HWSZ - 1);
    int y = pix >> 10;
    int x = pix & (NW - 1);
    const float* r0 = reg + (size_t)b * 2 * HWSZ;
    const float* r1 = r0 + HWSZ;
    float acc = 0.f;
#pragma unroll
    for (int i = 0; i < 11; i++) {
        int di = i - 5;
        int yy = y + di;
#pragma unroll
        for (int j = 0; j < 11; j++) {
            int dj = j - 5;
            if (di * di + dj * dj > 25) continue;   // cmask, exact integer test
            int xx = x + dj;
            bool in = (yy >= 0) && (yy < NH) && (xx >= 0) && (xx < NW);
            float rx = 0.f, ry = 0.f;
            if (in) {
                int q = yy * NW + xx;
                rx = r0[q];
                ry = r1[q];
            }
            float dx = __fsub_rn((float)dj, rx);
            float dy = __fsub_rn((float)di, ry);
            float s  = __fadd_rn(__fmul_rn(dx, dx), __fmul_rn(dy, dy));
            acc = __fadd_rn(acc, sqrtf(s));          // correctly-rounded sqrt
        }
    }
    float q = __fdiv_rn(acc, 81.0f);
    vote[p] = __fsub_rn(-q, 1.0f);
}

// ---------------- K3: 7x7 max pool, keep mask, center_map, key compaction ----------------
__global__ __launch_bounds__(256) void k_pool(const float* __restrict__ vote,
                                              float* __restrict__ cmap_out,
                                              u64* __restrict__ keys,
                                              int* __restrict__ ccnt,
                                              float thr_keep) {
    int p = blockIdx.x * 256 + threadIdx.x;
    if (p >= NB * HWSZ) return;
    int b = p >> 19;
    int pix = p & (HWSZ - 1);
    int y = pix >> 10;
    int x = pix & (NW - 1);
    const float* vb = vote + (size_t)b * HWSZ;
    float v = vb[pix];
    float mx = -INFINITY;
#pragma unroll
    for (int dy = -3; dy <= 3; dy++) {
        int yy = y + dy;
        if (yy < 0 || yy >= NH) continue;
#pragma unroll
        for (int dx = -3; dx <= 3; dx++) {
            int xx = x + dx;
            if (xx < 0 || xx >= NW) continue;
            float w = vb[yy * NW + xx];
            mx = fmaxf(mx, w);
        }
    }
    bool keep = (mx == v) && (v > thr_keep);
    cmap_out[p] = keep ? v : 0.0f;
    if (keep) {
        int pos = atomicAdd(&ccnt[b], 1);
        if (pos < CAPC) {
            unsigned u = __float_as_uint(v);
            unsigned ou = ((int)u < 0) ? ~u : (u | 0x80000000u);  // order-preserving map
            // key: value desc, then index asc; key==0 reserved as sentinel
            keys[(size_t)b * CAPC + pos] = ((u64)ou << 19) | (u64)(HWSZ - 1 - pix);
        }
    }
}

// Descending bitonic sort of a[0..np2) in LDS. np2 = power of 2, uniform.
// Keys unique (or 0 sentinel) -> deterministic result.
__device__ inline void bitonic_desc(u64* a, int np2, int tid, int T) {
    for (int k = 2; k <= np2; k <<= 1) {
        for (int j = k >> 1; j > 0; j >>= 1) {
            for (int i = tid; i < np2; i += T) {
                int ixj = i ^ j;
                if (ixj > i) {
                    u64 x = a[i], y = a[ixj];
                    bool up = ((i & k) == 0);
                    if (up ? (x < y) : (x > y)) { a[i] = y; a[ixj] = x; }
                }
            }
            __syncthreads();
        }
    }
}

// ---------------- K4: top-200 via LDS bitonic sort ----------------
__global__ __launch_bounds__(1024) void k_topk(const u64* __restrict__ keys_g,
                                               const int* __restrict__ ccnt,
                                               float* __restrict__ cxArr,
                                               float* __restrict__ cyArr,
                                               float* __restrict__ out_centers,
                                               float* __restrict__ out_topvals) {
    __shared__ u64 sk[CHUNK];
    __shared__ u64 cur[512];
    const int T = 1024;
    int b = blockIdx.x;
    int tid = threadIdx.x;
    int n = ccnt[b];
    if (n > CAPC) n = CAPC;
    const u64* Kg = keys_g + (size_t)b * CAPC;
    int nch = (n + CHUNK - 1) / CHUNK;
    if (nch < 1) nch = 1;
    if (tid < 512) cur[tid] = 0;
    __syncthreads();
    for (int ch = 0; ch < nch; ch++) {
        int off = ch * CHUNK;
        int len = n - off; if (len < 0) len = 0; if (len > CHUNK) len = CHUNK;
        int np2 = 256; while (np2 < len) np2 <<= 1;
        for (int c = tid; c < np2; c += T) sk[c] = (c < len) ? Kg[off + c] : 0;
        __syncthreads();
        bitonic_desc(sk, np2, tid, T);
        if (ch == 0) {
            if (tid < TK) cur[tid] = sk[tid];
            __syncthreads();
        } else {
            // merge running top-200 with this chunk's top-200: sort 512
            if (tid < TK) cur[TK + tid] = sk[tid];
            else if (tid < 512) { if (tid >= 2 * TK) cur[tid] = 0; }
            __syncthreads();
            bitonic_desc(cur, 512, tid, T);
        }
    }
    if (tid < TK) {
        u64 w = cur[tid];
        bool valid = (w != 0ULL);
        unsigned ou = (unsigned)(w >> 19);
        unsigned ub = (ou & 0x80000000u) ? (ou & 0x7FFFFFFFu) : ~ou;
        float v = __uint_as_float(ub);
        int pix = valid ? (int)(HWSZ - 1 - (int)(w & 0x7FFFFULL)) : 0x7fffffff;
        int ys = pix >> 10;
        int xs = pix & (NW - 1);
        cxArr[b * TK + tid] = valid ? (float)xs : 1e9f;
        cyArr[b * TK + tid] = valid ? (float)ys : 1e9f;
        out_centers[(b * TK + tid) * 2 + 0] = (float)ys;
        out_centers[(b * TK + tid) * 2 + 1] = (float)xs;
        out_topvals[b * TK + tid] = valid ? v : -INFINITY;
    }
}

// ---------------- K5: instance assignment + LDS-aggregated seg_counts ----------------
__global__ __launch_bounds__(256) void k_assign(const float* __restrict__ reg,
                                                const int* __restrict__ segid,
                                                const float* __restrict__ cxArr,
                                                const float* __restrict__ cyArr,
                                                float* __restrict__ out_inst,
                                                int* __restrict__ instid,
                                                int* __restrict__ segcnt) {
    __shared__ float scx[TK];
    __shared__ float scy[TK];
    __shared__ int lcnt[TK * NC];
    int tid = threadIdx.x;
    int base = blockIdx.x * ACH;           // ACH | HWSZ -> uniform b per block
    int b = base >> 19;
    if (tid < TK) {
        scx[tid] = cxArr[b * TK + tid];
        scy[tid] = cyArr[b * TK + tid];
    }
    for (int t = tid; t < TK * NC; t += 256) lcnt[t] = 0;
    __syncthreads();
    const float* r0 = reg + (size_t)b * 2 * HWSZ;
    const float* r1 = r0 + HWSZ;
    float px[4], py[4], bd[4];
    int bk[4];
#pragma unroll
    for (int it = 0; it < 4; it++) {
        int pix = (base & (HWSZ - 1)) + it * 256 + tid;
        int y = pix >> 10;
        int x = pix & (NW - 1);
        px[it] = __fsub_rn((float)(x + 1), r0[pix]);
        py[it] = __fsub_rn((float)(y + 1), r1[pix]);
        bd[it] = INFINITY; bk[it] = 0;
    }
#pragma unroll 4
    for (int k = 0; k < TK; k++) {
        float cx = scx[k];
        float cy = scy[k];
#pragma unroll
        for (int it = 0; it < 4; it++) {
            float dx = __fsub_rn(px[it], cx);
            float dy = __fsub_rn(py[it], cy);
            float d2 = __fadd_rn(__fmul_rn(dx, dx), __fmul_rn(dy, dy));
            if (d2 < bd[it]) { bd[it] = d2; bk[it] = k; }
        }
    }
#pragma unroll
    for (int it = 0; it < 4; it++) {
        int p = base + it * 256 + tid;
        int cls = segid[p];
        int thing = (cls >= 24) ? 1 : 0;
        int inst = (bk[it] + 1) * thing;
        out_inst[p] = (float)inst;
        instid[p] = inst;
        if (inst) atomicAdd(&lcnt[bk[it] * NC + cls], 1);
    }
    __syncthreads();
    for (int t = tid; t < TK * NC; t += 256) {
        int v = lcnt[t];
        if (v) atomicAdd(&segcnt[b * TK * NC + t], v);
    }
}

// ---------------- K6: per-instance class argmax + size ----------------
__global__ __launch_bounds__(256) void k_stats(const int* __restrict__ segcnt,
                                               float* __restrict__ out_icls,
                                               float* __restrict__ out_isize,
                                               int* __restrict__ icls,
                                               int* __restrict__ isize) {
    int t = blockIdx.x * 256 + threadIdx.x;
    if (t >= NB * TK) return;
    const int* row = segcnt + (size_t)t * NC;
    int total = 0; int bc = 0; int bv = -1;
#pragma unroll
    for (int c = 0; c < NC; c++) {
        int v = row[c];
        total += v;
        if (v > bv) { bv = v; bc = c; }
    }
    out_icls[t] = (float)bc;
    out_isize[t] = (float)total;
    icls[t] = bc;
    isize[t] = total;
}

// ---------------- K7: prob sum of selected class, LDS-aggregated ----------------
__global__ __launch_bounds__(256) void k_probsum(const float* __restrict__ logits,
                                                 const int* __restrict__ instid,
                                                 const float* __restrict__ mArr,
                                                 const float* __restrict__ dArr,
                                                 const int* __restrict__ icls,
                                                 float* __restrict__ probsum) {
    __shared__ float lps[TK];
    int tid = threadIdx.x;
    int base = blockIdx.x * ACH;
    int b = base >> 19;
    for (int t = tid; t < TK; t += 256) lps[t] = 0.f;
    __syncthreads();
#pragma unroll
    for (int it = 0; it < 4; it++) {
        int p = base + it * 256 + tid;
        int inst = instid[p];
        if (inst) {
            int pix = p & (HWSZ - 1);
            int c = icls[b * TK + inst - 1];
            float xv = logits[(size_t)(b * NC + c) * HWSZ + pix];
            float pr = __fdiv_rn(expf(__fsub_rn(xv, mArr[p])), dArr[p]);
            atomicAdd(&lps[inst - 1], pr);
        }
    }
    __syncthreads();
    for (int t = tid; t < TK; t += 256) {
        float s = lps[t];
        if (s != 0.f) atomicAdd(&probsum[b * TK + t], s);
    }
}

// ---------------- K8: finalize inst_seg_prob ----------------
__global__ __launch_bounds__(256) void k_final(const float* __restrict__ probsum,
                                               const int* __restrict__ isize,
                                               float* __restrict__ out_iprob) {
    int t = blockIdx.x * 256 + threadIdx.x;
    if (t >= NB * TK) return;
    float s = probsum[t];
    float sz = (float)isize[t];
    out_iprob[t] = __fdiv_rn(s, fmaxf(sz, 1.0f));
}

// ---------------- K0: zero accumulators ----------------
__global__ __launch_bounds__(256) void k_zero(int* __restrict__ ccnt,
                                              int* __restrict__ segcnt,
                                              float* __restrict__ probsum) {
    int t = blockIdx.x * 256 + threadIdx.x;
    if (t < NB) ccnt[t] = 0;
    if (t < NB * TK * NC) segcnt[t] = 0;
    if (t < NB * TK) probsum[t] = 0.f;
}

// Host: replicate _circle_constants threshold exactly (NumPy pairwise sum, f32)
static float compute_thr_keep() {
    float cdm[121];
    int t = 0;
    for (int i = 0; i < 11; i++) {
        for (int j = 0; j < 11; j++) {
            float ox = (float)(j - 5), oy = (float)(i - 5);
            float cd = sqrtf(ox * ox + oy * oy);
            float cm = (cd <= 5.0f) ? 1.0f : 0.0f;
            cdm[t++] = cd * cm;
        }
    }
    float r[8];
    for (int k = 0; k < 8; k++) r[k] = cdm[k];
    int i = 8;
    for (; i < 121 - (121 % 8); i += 8)
        for (int k = 0; k < 8; k++) r[k] += cdm[i + k];
    float res = ((r[0] + r[1]) + (r[2] + r[3])) + ((r[4] + r[5]) + (r[6] + r[7]));
    for (; i < 121; i++) res += cdm[i];
    float thr = res / 81.0f;
    double kt = -(double)thr - 1.0;
    return (float)kt;
}

extern "C" void kernel_launch(void* const* d_in, const int* in_sizes, int n_in,
                              void* d_out, int out_size, void* d_ws, size_t ws_size,
                              hipStream_t stream) {
    const float* logits = (const float*)d_in[0];
    const float* reg    = (const float*)d_in[2];
    float* out = (float*)d_out;

    // output layout (all f32)
    float* o_inst    = out;                       // B*HW
    float* o_seg     = out + 1048576;             // B*HW
    float* o_centers = out + 2097152;             // B*TK*2
    float* o_topvals = out + 2097952;             // B*TK
    float* o_icls    = out + 2098352;             // B*TK
    float* o_iprob   = out + 2098752;             // B*TK
    float* o_isize   = out + 2099152;             // B*TK
    float* o_cmap    = out + 2099552;             // B*HW

    // workspace layout: keys first (8B-aligned), then 4B arrays
    u64* keys = (u64*)d_ws;                                   // NB*CAPC
    float* wsf = (float*)(keys + (size_t)NB * CAPC);
    size_t o = 0;
    float* vote   = wsf + o; o += (size_t)NB * HWSZ;
    float* mArr   = wsf + o; o += (size_t)NB * HWSZ;
    float* dArr   = wsf + o; o += (size_t)NB * HWSZ;
    int*   segid  = (int*)(wsf + o); o += (size_t)NB * HWSZ;
    int*   instid = (int*)(wsf + o); o += (size_t)NB * HWSZ;
    int*   ccnt   = (int*)(wsf + o); o += 8;
    float* cxArr  = wsf + o; o += NB * TK;
    float* cyArr  = wsf + o; o += NB * TK;
    int*   segcnt = (int*)(wsf + o); o += (size_t)NB * TK * NC;
    float* probsum= wsf + o; o += NB * TK;
    int*   icls   = (int*)(wsf + o); o += NB * TK;
    int*   isize  = (int*)(wsf + o); o += NB * TK;

    float thr_keep = compute_thr_keep();

    int gridPix = (NB * HWSZ) / 256;   // 4096
    int gridAgg = (NB * HWSZ) / ACH;   // 1024

    k_zero<<<(NB * TK * NC + 255) / 256, 256, 0, stream>>>(ccnt, segcnt, probsum);
    k_seg<<<gridPix, 256, 0, stream>>>(logits, o_seg, segid, mArr, dArr);
    k_vote<<<gridPix, 256, 0, stream>>>(reg, vote);
    k_pool<<<gridPix, 256, 0, stream>>>(vote, o_cmap, keys, ccnt, thr_keep);
    k_topk<<<NB, 1024, 0, stream>>>(keys, ccnt, cxArr, cyArr, o_centers, o_topvals);
    k_assign<<<gridAgg, 256, 0, stream>>>(reg, segid, cxArr, cyArr, o_inst, instid, segcnt);
    k_stats<<<(NB * TK + 255) / 256, 256, 0, stream>>>(segcnt, o_icls, o_isize, icls, isize);
    k_probsum<<<gridAgg, 256, 0, stream>>>(logits, instid, mArr, dArr, icls, probsum);
    k_final<<<(NB * TK + 255) / 256, 256, 0, stream>>>(probsum, isize, o_iprob);
}